// Round 4
// baseline (243.014 us; speedup 1.0000x reference)
//
#include <hip/hip_runtime.h>
#include <cfloat>

#define NB 4
#define NN 4096
#define NC 256

typedef _Float16 f16;
typedef _Float16 f16x8 __attribute__((ext_vector_type(8)));
typedef float f32x16 __attribute__((ext_vector_type(16)));

__device__ __forceinline__ void gl_lds16(const void* g, void* l) {
    __builtin_amdgcn_global_load_lds(
        (const __attribute__((address_space(1))) unsigned int*)g,
        (__attribute__((address_space(3))) unsigned int*)l, 16, 0, 0);
}

// ---- prep: fp32 -> f16 hi/lo, interleaved per 8-elem granule + diag ----
// xhl[row] = 32 blocks of 32 B: [hi(8 f16) | lo(8 f16)] for k-granule gp.
// Row pitch 512 f16 = 1024 B. K=16 chunk kc = 64 B at offset kc*64:
// [hi k0-7][lo k0-7][hi k8-15][lo k8-15] = 4 slots of 16 B.
__global__ __launch_bounds__(256) void prep_kernel(const float* __restrict__ x,
                                                   f16* __restrict__ xhl,
                                                   float* __restrict__ diag) {
    const int lane = threadIdx.x & 63;
    const int wave = threadIdx.x >> 6;
    const int row  = (blockIdx.x << 2) + wave;            // 0..16383
    const float4 v = ((const float4*)(x + (size_t)row * NC))[lane];
    union { f16 h[4]; uint2 u; } H, L;
    float vv[4] = {v.x, v.y, v.z, v.w};
    float s = 0.f;
    #pragma unroll
    for (int k = 0; k < 4; ++k) {
        H.h[k] = (f16)vv[k];
        L.h[k] = (f16)(vv[k] - (float)H.h[k]);
        s = fmaf(vv[k], vv[k], s);
    }
    f16* base = xhl + (size_t)row * 512 + (lane >> 1) * 16 + (lane & 1) * 4;
    *(uint2*)base       = H.u;
    *(uint2*)(base + 8) = L.u;
    #pragma unroll
    for (int off = 32; off; off >>= 1) s += __shfl_xor(s, off, 64);
    if (lane == 0) diag[row] = s;
}

// ---------------- main MFMA kernel ----------------
// 256 blocks x 512 thr. Wave grid 1x8: wave tile 64 rows x 128 cols
// (2 rt x 4 ct of 32x32x16_f16, 3-term hi/lo). TJ=1024, KCB=16.
// LDS: A dbuf 2x4KB (streamed), B dbuf 2x64KB, St 6KB = 142 KB.
#define TI 64
#define TJ 1024
#define KCB 16
#define NCH (NC / KCB)   // 16
#define NJT (NN / TJ)    // 4
#define NQ  (NJT * NCH)  // 64

__device__ __forceinline__ void stage_chunk(const f16* __restrict__ xb, int i0,
                                            int q, f16* Abuf, f16* Bbuf,
                                            int w, int lane) {
    const int jt = q >> 4, kc = q & 15;
    const int j0 = jt * TJ;
    const int cl = lane >> 2;          // sub col/row 0..15
    const int sp = lane & 3;           // physical slot this lane fills
    #pragma unroll
    for (int it = 0; it < 8; ++it) {
        const int cb = (w * 8 + it) * 16;
        const int c  = cb + cl;
        const int sl = sp ^ ((c >> 1) & 3);          // logical slot stored here
        gl_lds16(xb + (size_t)(j0 + c) * 512 + kc * 32 + sl * 8, Bbuf + cb * 32);
    }
    if (w < 4) {
        const int rb = w * 16;
        const int r  = rb + cl;
        const int sl = sp ^ ((r >> 1) & 3);
        gl_lds16(xb + (size_t)(i0 + r) * 512 + kc * 32 + sl * 8, Abuf + rb * 32);
    }
}

__global__ __launch_bounds__(512, 2) void fcm_mfma(const f16* __restrict__ xhl,
                                                   const float* __restrict__ diag,
                                                   float* __restrict__ out) {
    __shared__ f16 Asd[2][TI * 32];      //  8 KB
    __shared__ f16 Bsd[2][TJ * 32];      // 128 KB
    __shared__ float St[TI * 8 * 3];     //   6 KB  persistent per-(row,wave) top-2

    const int tid   = threadIdx.x;
    const int bx    = blockIdx.x;
    const int batch = (bx & 7) >> 1;                  // batch -> XCD pair (L2 locality)
    const int band  = ((bx >> 3) << 1) | (bx & 1);    // 0..63
    const int i0    = band * TI;

    const f16* __restrict__ xb   = xhl + (size_t)batch * NN * 512;
    const float* __restrict__ db = diag + (size_t)batch * NN;

    const int w    = tid >> 6;     // 0..7: col slice of 128
    const int lane = tid & 63;
    const int gh   = lane >> 5;    // K-granule half / C-row group
    const int l31  = lane & 31;

    // init persistent state (FLT_MAX bits == huge positive int for the idx slot)
    for (int idx = tid; idx < TI * 8 * 3; idx += 512) St[idx] = FLT_MAX;

    stage_chunk(xb, i0, 0, Asd[0], Bsd[0], w, lane);

    for (int jt = 0; jt < NJT; ++jt) {
        f32x16 acc[2][4];
        #pragma unroll
        for (int rt = 0; rt < 2; ++rt)
            #pragma unroll
            for (int ct = 0; ct < 4; ++ct)
                #pragma unroll
                for (int p = 0; p < 16; ++p) acc[rt][ct][p] = 0.f;

        for (int kc = 0; kc < NCH; ++kc) {
            const int q = jt * NCH + kc;
            __syncthreads();                 // drains staging issued a full chunk ago
            if (q + 1 < NQ)
                stage_chunk(xb, i0, q + 1, Asd[(q + 1) & 1], Bsd[(q + 1) & 1], w, lane);

            const f16* Ab = Asd[q & 1];
            const f16* Bb = Bsd[q & 1];
            f16x8 afh[2], afl[2], bfh[4], bfl[4];
            #pragma unroll
            for (int rt = 0; rt < 2; ++rt) {
                const int r  = rt * 32 + l31;
                const int sw = (r >> 1) & 3;
                afh[rt] = *(const f16x8*)&Ab[r * 32 + (((gh << 1) | 0) ^ sw) * 8];
                afl[rt] = *(const f16x8*)&Ab[r * 32 + (((gh << 1) | 1) ^ sw) * 8];
            }
            #pragma unroll
            for (int ct = 0; ct < 4; ++ct) {
                const int c  = w * 128 + ct * 32 + l31;
                const int sw = (c >> 1) & 3;
                bfh[ct] = *(const f16x8*)&Bb[c * 32 + (((gh << 1) | 0) ^ sw) * 8];
                bfl[ct] = *(const f16x8*)&Bb[c * 32 + (((gh << 1) | 1) ^ sw) * 8];
            }
            // 3 dependency-separated passes: 8 independent acc chains each
            #pragma unroll
            for (int rt = 0; rt < 2; ++rt)
                #pragma unroll
                for (int ct = 0; ct < 4; ++ct)
                    acc[rt][ct] = __builtin_amdgcn_mfma_f32_32x32x16_f16(afh[rt], bfh[ct], acc[rt][ct], 0, 0, 0);
            #pragma unroll
            for (int rt = 0; rt < 2; ++rt)
                #pragma unroll
                for (int ct = 0; ct < 4; ++ct)
                    acc[rt][ct] = __builtin_amdgcn_mfma_f32_32x32x16_f16(afh[rt], bfl[ct], acc[rt][ct], 0, 0, 0);
            #pragma unroll
            for (int rt = 0; rt < 2; ++rt)
                #pragma unroll
                for (int ct = 0; ct < 4; ++ct)
                    acc[rt][ct] = __builtin_amdgcn_mfma_f32_32x32x16_f16(afl[rt], bfh[ct], acc[rt][ct], 0, 0, 0);
        }

        // ---- fold this j-tile: transient per-lane top-2 over 32 row-slots ----
        float t1[32], t2[32]; int ti_[32];
        #pragma unroll
        for (int s = 0; s < 32; ++s) { t1[s] = FLT_MAX; t2[s] = FLT_MAX; ti_[s] = 0x7fffffff; }
        #pragma unroll
        for (int ct = 0; ct < 4; ++ct) {
            const int c = w * 128 + ct * 32 + l31;
            const int j = jt * TJ + c;
            const float dj = db[j];
            #pragma unroll
            for (int rt = 0; rt < 2; ++rt) {
                #pragma unroll
                for (int reg = 0; reg < 16; ++reg) {
                    const int rloc = rt * 32 + (gh << 2) + (reg & 3) + ((reg >> 2) << 3);
                    float v = fmaf(-2.0f, acc[rt][ct][reg], dj);
                    v = (j == i0 + rloc) ? FLT_MAX : v;      // mask self
                    const int s = rt * 16 + reg;
                    const bool lt = v < t1[s];               // strict: ascending j
                    t2[s] = fminf(t2[s], fmaxf(t1[s], v));
                    t1[s] = fminf(t1[s], v);
                    ti_[s] = lt ? j : ti_[s];
                }
            }
        }
        // butterfly across the 32 col-lanes (masks < 32 stay within gh half)
        #pragma unroll
        for (int s = 0; s < 32; ++s) {
            float a1 = t1[s], a2 = t2[s]; int ai = ti_[s];
            #pragma unroll
            for (int msk = 1; msk < 32; msk <<= 1) {
                const float o1 = __shfl_xor(a1, msk, 64);
                const float o2 = __shfl_xor(a2, msk, 64);
                const int   oi = __shfl_xor(ai, msk, 64);
                const bool take = (o1 < a1) || (o1 == a1 && oi < ai);
                const float keep = take ? a1 : o1;
                a2 = fminf(fminf(a2, o2), keep);
                a1 = take ? o1 : a1;
                ai = take ? oi : ai;
            }
            t1[s] = a1; t2[s] = a2; ti_[s] = ai;
        }
        // lane l31 takes slot l31 (post-butterfly state is lane-uniform per gh)
        float r1 = t1[0], r2 = t2[0]; int ri = ti_[0];
        #pragma unroll
        for (int s = 1; s < 32; ++s) {
            const bool sel = (l31 == s);
            r1 = sel ? t1[s] : r1;
            r2 = sel ? t2[s] : r2;
            ri = sel ? ti_[s] : ri;
        }
        // slot -> row; RMW into this wave's St column (rows disjoint across lanes)
        {
            const int s_rt = l31 >> 4, s_reg = l31 & 15;
            const int rrow = s_rt * 32 + (gh << 2) + (s_reg & 3) + ((s_reg >> 2) << 3);
            float* p = &St[(rrow * 8 + w) * 3];
            const float o1 = p[0]; const int oi = __float_as_int(p[1]); const float o2 = p[2];
            const bool take = (o1 < r1) || (o1 == r1 && oi < ri);
            const float keep = take ? r1 : o1;
            p[0] = take ? o1 : r1;
            p[1] = __int_as_float(take ? oi : ri);
            p[2] = fminf(fminf(r2, o2), keep);
        }
    }

    __syncthreads();
    if (tid < TI) {
        float M1 = FLT_MAX, M2 = FLT_MAX; int I1 = 0x7fffffff;
        #pragma unroll
        for (int t = 0; t < 8; ++t) {
            const float* p = &St[(tid * 8 + t) * 3];
            const float o1 = p[0]; const int oi = __float_as_int(p[1]); const float o2 = p[2];
            const bool take = (o1 < M1) || (o1 == M1 && oi < I1);
            const float keep = take ? M1 : o1;
            M2 = fminf(fminf(M2, o2), keep);
            M1 = take ? o1 : M1;
            I1 = take ? oi : I1;
        }
        const int   gi = i0 + tid;
        const float di = db[gi];
        const float d1 = sqrtf(fmaxf(di + M1, 0.0f) + 1e-9f);
        const float d2 = sqrtf(fmaxf(di + M2, 0.0f) + 1e-9f);
        const float e  = expf(d1);
        const float pred = (d1 / d2 < 0.6f) ? 2.0f / (1.0f + e)
                                            : 2.0f / (1.0f + 2.0f * e);
        out[(size_t)batch * NN + gi] = pred;
        out[(size_t)NB * NN + (size_t)batch * NN + gi] = (float)I1;
    }
}

// ---------------- fp32 fallback (round-1, known-correct) if ws too small ----------------
__global__ __launch_bounds__(256) void diag_kernel(const float* __restrict__ x,
                                                   float* __restrict__ diag) {
    const int lane = threadIdx.x & 63;
    const int wave = threadIdx.x >> 6;
    const int row  = (blockIdx.x << 2) + wave;
    const float4 v = ((const float4*)(x + (size_t)row * NC))[lane];
    float s = v.x * v.x + v.y * v.y + v.z * v.z + v.w * v.w;
    #pragma unroll
    for (int off = 32; off; off >>= 1) s += __shfl_xor(s, off, 64);
    if (lane == 0) diag[row] = s;
}

#define FTI 64
#define FTJ 256
#define FKC 16

__global__ __launch_bounds__(256) void fcm_fallback(const float* __restrict__ x,
                                                    const float* __restrict__ diag,
                                                    float* __restrict__ out) {
    __shared__ float Asf[FKC * FTI];
    __shared__ float Bsf[FKC * FTJ];
    __shared__ float Dsf[FTJ];
    __shared__ float Scrf[FTI * 32 * 3];

    const int tid = threadIdx.x;
    const int bx  = blockIdx.x;
    const int batch = (bx & 7) >> 1;
    const int tile  = ((bx >> 3) << 1) | (bx & 1);
    const int i0    = tile * FTI;
    const float* __restrict__ xbf = x + (size_t)batch * NN * NC;
    const float* __restrict__ dbf = diag + (size_t)batch * NN;
    const int tx = tid & 31;
    const int ty = tid >> 5;
    const int sr  = tid & 63;
    const int sk0 = (tid >> 6) << 2;

    float m1[8], m2[8]; int i1[8];
    #pragma unroll
    for (int r = 0; r < 8; ++r) { m1[r] = FLT_MAX; m2[r] = FLT_MAX; i1[r] = 0; }

    for (int jt = 0; jt < NN / FTJ; ++jt) {
        const int j0 = jt * FTJ;
        __syncthreads();
        Dsf[tid] = dbf[j0 + tid];
        float acc[8][8];
        #pragma unroll
        for (int r = 0; r < 8; ++r)
            #pragma unroll
            for (int c = 0; c < 8; ++c) acc[r][c] = 0.0f;
        float4 pa  = *(const float4*)(xbf + (size_t)(i0 + sr) * NC + sk0);
        const float* bsrc = xbf + (size_t)(j0 + tid) * NC;
        float4 pb0 = *(const float4*)(bsrc + 0);
        float4 pb1 = *(const float4*)(bsrc + 4);
        float4 pb2 = *(const float4*)(bsrc + 8);
        float4 pb3 = *(const float4*)(bsrc + 12);
        for (int kc = 0; kc < NC / FKC; ++kc) {
            __syncthreads();
            Asf[(sk0 + 0) * FTI + sr] = pa.x;
            Asf[(sk0 + 1) * FTI + sr] = pa.y;
            Asf[(sk0 + 2) * FTI + sr] = pa.z;
            Asf[(sk0 + 3) * FTI + sr] = pa.w;
            Bsf[ 0 * FTJ + tid] = pb0.x; Bsf[ 1 * FTJ + tid] = pb0.y;
            Bsf[ 2 * FTJ + tid] = pb0.z; Bsf[ 3 * FTJ + tid] = pb0.w;
            Bsf[ 4 * FTJ + tid] = pb1.x; Bsf[ 5 * FTJ + tid] = pb1.y;
            Bsf[ 6 * FTJ + tid] = pb1.z; Bsf[ 7 * FTJ + tid] = pb1.w;
            Bsf[ 8 * FTJ + tid] = pb2.x; Bsf[ 9 * FTJ + tid] = pb2.y;
            Bsf[10 * FTJ + tid] = pb2.z; Bsf[11 * FTJ + tid] = pb2.w;
            Bsf[12 * FTJ + tid] = pb3.x; Bsf[13 * FTJ + tid] = pb3.y;
            Bsf[14 * FTJ + tid] = pb3.z; Bsf[15 * FTJ + tid] = pb3.w;
            if (kc + 1 < NC / FKC) {
                const int kb = (kc + 1) * FKC;
                pa  = *(const float4*)(xbf + (size_t)(i0 + sr) * NC + kb + sk0);
                pb0 = *(const float4*)(bsrc + kb + 0);
                pb1 = *(const float4*)(bsrc + kb + 4);
                pb2 = *(const float4*)(bsrc + kb + 8);
                pb3 = *(const float4*)(bsrc + kb + 12);
            }
            __syncthreads();
            #pragma unroll
            for (int k = 0; k < FKC; ++k) {
                float av[8], bv[8];
                *(float4*)&av[0] = *(const float4*)&Asf[k * FTI + ty * 8];
                *(float4*)&av[4] = *(const float4*)&Asf[k * FTI + ty * 8 + 4];
                *(float4*)&bv[0] = *(const float4*)&Bsf[k * FTJ + tx * 8];
                *(float4*)&bv[4] = *(const float4*)&Bsf[k * FTJ + tx * 8 + 4];
                #pragma unroll
                for (int r = 0; r < 8; ++r)
                    #pragma unroll
                    for (int c = 0; c < 8; ++c)
                        acc[r][c] = fmaf(av[r], bv[c], acc[r][c]);
            }
        }
        #pragma unroll
        for (int c = 0; c < 8; ++c) {
            const int j = j0 + tx * 8 + c;
            const float dj = Dsf[tx * 8 + c];
            #pragma unroll
            for (int r = 0; r < 8; ++r) {
                const int ig = i0 + ty * 8 + r;
                float v = fmaf(-2.0f, acc[r][c], dj);
                v = (j == ig) ? FLT_MAX : v;
                const bool lt = v < m1[r];
                m2[r] = fminf(m2[r], fmaxf(m1[r], v));
                m1[r] = fminf(m1[r], v);
                i1[r] = lt ? j : i1[r];
            }
        }
    }
    __syncthreads();
    #pragma unroll
    for (int r = 0; r < 8; ++r) {
        float* s = &Scrf[((ty * 8 + r) * 32 + tx) * 3];
        s[0] = m1[r]; s[1] = __int_as_float(i1[r]); s[2] = m2[r];
    }
    __syncthreads();
    if (tid < FTI) {
        float M1 = FLT_MAX, M2 = FLT_MAX; int I1 = 0;
        for (int t = 0; t < 32; ++t) {
            const float* s = &Scrf[(tid * 32 + t) * 3];
            const float v1 = s[0]; const int ii = __float_as_int(s[1]);
            const float v2 = s[2];
            if (v1 < M1 || (v1 == M1 && ii < I1)) {
                M2 = fminf(M2, M1); M1 = v1; I1 = ii;
            } else {
                M2 = fminf(M2, v1);
            }
            M2 = fminf(M2, v2);
        }
        const int   gi = i0 + tid;
        const float di = dbf[gi];
        const float d1 = sqrtf(fmaxf(di + M1, 0.0f) + 1e-9f);
        const float d2 = sqrtf(fmaxf(di + M2, 0.0f) + 1e-9f);
        const float e  = expf(d1);
        const float pred = (d1 / d2 < 0.6f) ? 2.0f / (1.0f + e)
                                            : 2.0f / (1.0f + 2.0f * e);
        out[(size_t)batch * NN + gi] = pred;
        out[(size_t)NB * NN + (size_t)batch * NN + gi] = (float)I1;
    }
}

extern "C" void kernel_launch(void* const* d_in, const int* in_sizes, int n_in,
                              void* d_out, int out_size, void* d_ws, size_t ws_size,
                              hipStream_t stream) {
    const float* x = (const float*)d_in[0];
    float* out     = (float*)d_out;
    const size_t n_elem = (size_t)NB * NN * NC;
    const size_t need   = n_elem * 4 + (size_t)NB * NN * 4;   // interleaved hi/lo f16 + diag
    if (ws_size >= need) {
        f16*   xhl  = (f16*)d_ws;
        float* diag = (float*)(xhl + n_elem * 2);
        prep_kernel<<<dim3(NB * NN / 4), dim3(256), 0, stream>>>(x, xhl, diag);
        fcm_mfma<<<dim3(256), dim3(512), 0, stream>>>(xhl, diag, out);
    } else {
        float* diag = (float*)d_ws;
        diag_kernel<<<dim3(NB * NN / 4), dim3(256), 0, stream>>>(x, diag);
        fcm_fallback<<<dim3(256), dim3(256), 0, stream>>>(x, diag, out);
    }
}

// Round 5
// 228.265 us; speedup vs baseline: 1.0646x; 1.0646x over previous
//
#include <hip/hip_runtime.h>
#include <cfloat>

#define NB 4
#define NN 4096
#define NC 256

typedef _Float16 f16;
typedef _Float16 f16x8 __attribute__((ext_vector_type(8)));
typedef float f32x16 __attribute__((ext_vector_type(16)));

__device__ __forceinline__ void gl_lds16(const void* g, void* l) {
    __builtin_amdgcn_global_load_lds(
        (const __attribute__((address_space(1))) unsigned int*)g,
        (__attribute__((address_space(3))) unsigned int*)l, 16, 0, 0);
}

// ---- prep: fp32 -> f16 hi/lo, interleaved per 8-elem granule + diag ----
// xhl[row] = 32 blocks of 32 B: [hi(8 f16) | lo(8 f16)]. Row pitch 1024 B.
// K=16 chunk kc = 64 B at kc*64: 4 slots of 16 B [hi k0-7][lo k0-7][hi k8-15][lo k8-15].
__global__ __launch_bounds__(256) void prep_kernel(const float* __restrict__ x,
                                                   f16* __restrict__ xhl,
                                                   float* __restrict__ diag) {
    const int lane = threadIdx.x & 63;
    const int wave = threadIdx.x >> 6;
    const int row  = (blockIdx.x << 2) + wave;            // 0..16383
    const float4 v = ((const float4*)(x + (size_t)row * NC))[lane];
    union { f16 h[4]; uint2 u; } H, L;
    float vv[4] = {v.x, v.y, v.z, v.w};
    float s = 0.f;
    #pragma unroll
    for (int k = 0; k < 4; ++k) {
        H.h[k] = (f16)vv[k];
        L.h[k] = (f16)(vv[k] - (float)H.h[k]);
        s = fmaf(vv[k], vv[k], s);
    }
    f16* base = xhl + (size_t)row * 512 + (lane >> 1) * 16 + (lane & 1) * 4;
    *(uint2*)base       = H.u;
    *(uint2*)(base + 8) = L.u;
    #pragma unroll
    for (int off = 32; off; off >>= 1) s += __shfl_xor(s, off, 64);
    if (lane == 0) diag[row] = s;
}

// ---------------- main MFMA kernel ----------------
// Grid 512 = 4 batch x 64 band x 2 j-half; 256 thr (4 waves), wave tile 64x128.
// LDS: A dbuf 2x4KB + B dbuf 2x32KB + St 3KB = 75 KB -> 2 blocks/CU.
#define TI 64
#define TJ 512
#define JH 2048          // j-range per block
#define KCB 16
#define NCH (NC / KCB)   // 16
#define NJT (JH / TJ)    // 4
#define NQ  (NJT * NCH)  // 64

__device__ __forceinline__ void stage_chunk(const f16* __restrict__ xb, int i0,
                                            int jbase, int q, f16* Abuf, f16* Bbuf,
                                            int w, int lane) {
    const int kc = q & 15;
    const int j0 = jbase + (q >> 4) * TJ;
    const int cl = lane >> 2;          // sub col/row 0..15
    const int sp = lane & 3;           // physical slot this lane fills
    #pragma unroll
    for (int it = 0; it < 8; ++it) {
        const int cb = (w * 8 + it) * 16;
        const int c  = cb + cl;
        const int sl = sp ^ ((c >> 1) & 3);          // logical slot stored here
        gl_lds16(xb + (size_t)(j0 + c) * 512 + kc * 32 + sl * 8, Bbuf + cb * 32);
    }
    {
        const int rb = w * 16;
        const int r  = rb + cl;
        const int sl = sp ^ ((r >> 1) & 3);
        gl_lds16(xb + (size_t)(i0 + r) * 512 + kc * 32 + sl * 8, Abuf + rb * 32);
    }
}

__global__ __launch_bounds__(256, 2) void fcm_mfma(const f16* __restrict__ xhl,
                                                   const float* __restrict__ diag,
                                                   float* __restrict__ part) {
    __shared__ f16 Asd[2][TI * 32];      //  8 KB
    __shared__ f16 Bsd[2][TJ * 32];      // 64 KB
    __shared__ float St[TI * 4 * 3];     //  3 KB  per-(row,wave) running top-2

    const int tid   = threadIdx.x;
    const int bx    = blockIdx.x;
    const int batch = (bx & 7) >> 1;     // batch -> XCD pair (L2 locality)
    const int jh    = bx & 1;            // j-half
    const int band  = bx >> 3;           // 0..63
    const int i0    = band * TI;
    const int jbase = jh * JH;

    const f16* __restrict__ xb   = xhl + (size_t)batch * NN * 512;
    const float* __restrict__ db = diag + (size_t)batch * NN;

    const int w    = tid >> 6;     // 0..3: col slice of 128
    const int lane = tid & 63;
    const int gh   = lane >> 5;
    const int l31  = lane & 31;

    for (int idx = tid; idx < TI * 4 * 3; idx += 256) St[idx] = FLT_MAX;

    stage_chunk(xb, i0, jbase, 0, Asd[0], Bsd[0], w, lane);

    for (int jt = 0; jt < NJT; ++jt) {
        f32x16 acc[2][4];
        #pragma unroll
        for (int rt = 0; rt < 2; ++rt)
            #pragma unroll
            for (int ct = 0; ct < 4; ++ct)
                #pragma unroll
                for (int p = 0; p < 16; ++p) acc[rt][ct][p] = 0.f;

        for (int kc = 0; kc < NCH; ++kc) {
            const int q = jt * NCH + kc;
            __syncthreads();             // drains staging issued one chunk ago
            if (q + 1 < NQ)
                stage_chunk(xb, i0, jbase, q + 1, Asd[(q + 1) & 1], Bsd[(q + 1) & 1], w, lane);

            const f16* Ab = Asd[q & 1];
            const f16* Bb = Bsd[q & 1];
            f16x8 afh[2], afl[2], bfh[4], bfl[4];
            #pragma unroll
            for (int rt = 0; rt < 2; ++rt) {
                const int r  = rt * 32 + l31;
                const int sw = (r >> 1) & 3;
                afh[rt] = *(const f16x8*)&Ab[r * 32 + (((gh << 1) | 0) ^ sw) * 8];
                afl[rt] = *(const f16x8*)&Ab[r * 32 + (((gh << 1) | 1) ^ sw) * 8];
            }
            #pragma unroll
            for (int ct = 0; ct < 4; ++ct) {
                const int c  = w * 128 + ct * 32 + l31;
                const int sw = (c >> 1) & 3;
                bfh[ct] = *(const f16x8*)&Bb[c * 32 + (((gh << 1) | 0) ^ sw) * 8];
                bfl[ct] = *(const f16x8*)&Bb[c * 32 + (((gh << 1) | 1) ^ sw) * 8];
            }
            // 3 dependency-separated passes of 8 independent chains
            #pragma unroll
            for (int rt = 0; rt < 2; ++rt)
                #pragma unroll
                for (int ct = 0; ct < 4; ++ct)
                    acc[rt][ct] = __builtin_amdgcn_mfma_f32_32x32x16_f16(afh[rt], bfh[ct], acc[rt][ct], 0, 0, 0);
            #pragma unroll
            for (int rt = 0; rt < 2; ++rt)
                #pragma unroll
                for (int ct = 0; ct < 4; ++ct)
                    acc[rt][ct] = __builtin_amdgcn_mfma_f32_32x32x16_f16(afh[rt], bfl[ct], acc[rt][ct], 0, 0, 0);
            #pragma unroll
            for (int rt = 0; rt < 2; ++rt)
                #pragma unroll
                for (int ct = 0; ct < 4; ++ct)
                    acc[rt][ct] = __builtin_amdgcn_mfma_f32_32x32x16_f16(afl[rt], bfh[ct], acc[rt][ct], 0, 0, 0);
        }

        // ---- fused fold: per slot insert-4 -> butterfly -> select (no big temps) ----
        int jv[4]; float djv[4];
        #pragma unroll
        for (int ct = 0; ct < 4; ++ct) {
            jv[ct]  = jbase + jt * TJ + w * 128 + ct * 32 + l31;
            djv[ct] = db[jv[ct]];
        }
        float r1 = FLT_MAX, r2 = FLT_MAX; int ri = 0x7fffffff;
        #pragma unroll
        for (int s = 0; s < 32; ++s) {
            const int rt  = s >> 4, reg = s & 15;
            const int rg  = i0 + rt * 32 + (gh << 2) + (reg & 3) + ((reg >> 2) << 3);
            float a1 = FLT_MAX, a2 = FLT_MAX; int ai = 0x7fffffff;
            #pragma unroll
            for (int ct = 0; ct < 4; ++ct) {
                float v = fmaf(-2.0f, acc[rt][ct][reg], djv[ct]);
                v = (jv[ct] == rg) ? FLT_MAX : v;      // mask self
                const bool lt = v < a1;                // strict: ascending j
                a2 = fminf(a2, fmaxf(a1, v));
                a1 = fminf(a1, v);
                ai = lt ? jv[ct] : ai;
            }
            #pragma unroll
            for (int msk = 1; msk < 32; msk <<= 1) {   // stays within gh half
                const float o1 = __shfl_xor(a1, msk, 64);
                const float o2 = __shfl_xor(a2, msk, 64);
                const int   oi = __shfl_xor(ai, msk, 64);
                const bool take = (o1 < a1) || (o1 == a1 && oi < ai);
                const float keep = take ? a1 : o1;
                a2 = fminf(fminf(a2, o2), keep);
                a1 = take ? o1 : a1;
                ai = take ? oi : ai;
            }
            const bool sel = (l31 == s);
            r1 = sel ? a1 : r1;
            r2 = sel ? a2 : r2;
            ri = sel ? ai : ri;
        }
        {   // RMW this wave's St column; rows disjoint across lanes
            const int s_rt = l31 >> 4, s_reg = l31 & 15;
            const int rrow = s_rt * 32 + (gh << 2) + (s_reg & 3) + ((s_reg >> 2) << 3);
            float* p = &St[(rrow * 4 + w) * 3];
            const float o1 = p[0]; const int oi = __float_as_int(p[1]); const float o2 = p[2];
            const bool take = (o1 < r1) || (o1 == r1 && oi < ri);
            const float keep = take ? r1 : o1;
            p[0] = take ? o1 : r1;
            p[1] = __int_as_float(take ? oi : ri);
            p[2] = fminf(fminf(r2, o2), keep);
        }
    }

    __syncthreads();
    if (tid < TI) {
        float M1 = FLT_MAX, M2 = FLT_MAX; int I1 = 0x7fffffff;
        #pragma unroll
        for (int t = 0; t < 4; ++t) {
            const float* p = &St[(tid * 4 + t) * 3];
            const float o1 = p[0]; const int oi = __float_as_int(p[1]); const float o2 = p[2];
            const bool take = (o1 < M1) || (o1 == M1 && oi < I1);
            const float keep = take ? M1 : o1;
            M2 = fminf(fminf(M2, o2), keep);
            M1 = take ? o1 : M1;
            I1 = take ? oi : I1;
        }
        float* q = part + (((size_t)batch * NN + i0 + tid) * 2 + jh) * 3;
        q[0] = M1; q[1] = __int_as_float(I1); q[2] = M2;
    }
}

// ---- combine the two j-half partials, compute outputs ----
__global__ __launch_bounds__(256) void combine_kernel(const float* __restrict__ part,
                                                      const float* __restrict__ diag,
                                                      float* __restrict__ out) {
    const int g = blockIdx.x * 256 + threadIdx.x;      // 0..16383
    float M1 = FLT_MAX, M2 = FLT_MAX; int I1 = 0x7fffffff;
    #pragma unroll
    for (int h = 0; h < 2; ++h) {
        const float* p = part + ((size_t)g * 2 + h) * 3;
        const float o1 = p[0]; const int oi = __float_as_int(p[1]); const float o2 = p[2];
        const bool take = (o1 < M1) || (o1 == M1 && oi < I1);
        const float keep = take ? M1 : o1;
        M2 = fminf(fminf(M2, o2), keep);
        M1 = take ? o1 : M1;
        I1 = take ? oi : I1;
    }
    const float di = diag[g];
    const float d1 = sqrtf(fmaxf(di + M1, 0.0f) + 1e-9f);
    const float d2 = sqrtf(fmaxf(di + M2, 0.0f) + 1e-9f);
    const float e  = expf(d1);
    const float pred = (d1 / d2 < 0.6f) ? 2.0f / (1.0f + e)
                                        : 2.0f / (1.0f + 2.0f * e);
    out[g] = pred;
    out[(size_t)NB * NN + g] = (float)I1;
}

// ---------------- fp32 fallback (round-1, known-correct) if ws too small ----------------
__global__ __launch_bounds__(256) void diag_kernel(const float* __restrict__ x,
                                                   float* __restrict__ diag) {
    const int lane = threadIdx.x & 63;
    const int wave = threadIdx.x >> 6;
    const int row  = (blockIdx.x << 2) + wave;
    const float4 v = ((const float4*)(x + (size_t)row * NC))[lane];
    float s = v.x * v.x + v.y * v.y + v.z * v.z + v.w * v.w;
    #pragma unroll
    for (int off = 32; off; off >>= 1) s += __shfl_xor(s, off, 64);
    if (lane == 0) diag[row] = s;
}

#define FTI 64
#define FTJ 256
#define FKC 16

__global__ __launch_bounds__(256) void fcm_fallback(const float* __restrict__ x,
                                                    const float* __restrict__ diag,
                                                    float* __restrict__ out) {
    __shared__ float Asf[FKC * FTI];
    __shared__ float Bsf[FKC * FTJ];
    __shared__ float Dsf[FTJ];
    __shared__ float Scrf[FTI * 32 * 3];

    const int tid = threadIdx.x;
    const int bx  = blockIdx.x;
    const int batch = (bx & 7) >> 1;
    const int tile  = ((bx >> 3) << 1) | (bx & 1);
    const int i0    = tile * FTI;
    const float* __restrict__ xbf = x + (size_t)batch * NN * NC;
    const float* __restrict__ dbf = diag + (size_t)batch * NN;
    const int tx = tid & 31;
    const int ty = tid >> 5;
    const int sr  = tid & 63;
    const int sk0 = (tid >> 6) << 2;

    float m1[8], m2[8]; int i1[8];
    #pragma unroll
    for (int r = 0; r < 8; ++r) { m1[r] = FLT_MAX; m2[r] = FLT_MAX; i1[r] = 0; }

    for (int jt = 0; jt < NN / FTJ; ++jt) {
        const int j0 = jt * FTJ;
        __syncthreads();
        Dsf[tid] = dbf[j0 + tid];
        float acc[8][8];
        #pragma unroll
        for (int r = 0; r < 8; ++r)
            #pragma unroll
            for (int c = 0; c < 8; ++c) acc[r][c] = 0.0f;
        float4 pa  = *(const float4*)(xbf + (size_t)(i0 + sr) * NC + sk0);
        const float* bsrc = xbf + (size_t)(j0 + tid) * NC;
        float4 pb0 = *(const float4*)(bsrc + 0);
        float4 pb1 = *(const float4*)(bsrc + 4);
        float4 pb2 = *(const float4*)(bsrc + 8);
        float4 pb3 = *(const float4*)(bsrc + 12);
        for (int kc = 0; kc < NC / FKC; ++kc) {
            __syncthreads();
            Asf[(sk0 + 0) * FTI + sr] = pa.x;
            Asf[(sk0 + 1) * FTI + sr] = pa.y;
            Asf[(sk0 + 2) * FTI + sr] = pa.z;
            Asf[(sk0 + 3) * FTI + sr] = pa.w;
            Bsf[ 0 * FTJ + tid] = pb0.x; Bsf[ 1 * FTJ + tid] = pb0.y;
            Bsf[ 2 * FTJ + tid] = pb0.z; Bsf[ 3 * FTJ + tid] = pb0.w;
            Bsf[ 4 * FTJ + tid] = pb1.x; Bsf[ 5 * FTJ + tid] = pb1.y;
            Bsf[ 6 * FTJ + tid] = pb1.z; Bsf[ 7 * FTJ + tid] = pb1.w;
            Bsf[ 8 * FTJ + tid] = pb2.x; Bsf[ 9 * FTJ + tid] = pb2.y;
            Bsf[10 * FTJ + tid] = pb2.z; Bsf[11 * FTJ + tid] = pb2.w;
            Bsf[12 * FTJ + tid] = pb3.x; Bsf[13 * FTJ + tid] = pb3.y;
            Bsf[14 * FTJ + tid] = pb3.z; Bsf[15 * FTJ + tid] = pb3.w;
            if (kc + 1 < NC / FKC) {
                const int kb = (kc + 1) * FKC;
                pa  = *(const float4*)(xbf + (size_t)(i0 + sr) * NC + kb + sk0);
                pb0 = *(const float4*)(bsrc + kb + 0);
                pb1 = *(const float4*)(bsrc + kb + 4);
                pb2 = *(const float4*)(bsrc + kb + 8);
                pb3 = *(const float4*)(bsrc + kb + 12);
            }
            __syncthreads();
            #pragma unroll
            for (int k = 0; k < FKC; ++k) {
                float av[8], bv[8];
                *(float4*)&av[0] = *(const float4*)&Asf[k * FTI + ty * 8];
                *(float4*)&av[4] = *(const float4*)&Asf[k * FTI + ty * 8 + 4];
                *(float4*)&bv[0] = *(const float4*)&Bsf[k * FTJ + tx * 8];
                *(float4*)&bv[4] = *(const float4*)&Bsf[k * FTJ + tx * 8 + 4];
                #pragma unroll
                for (int r = 0; r < 8; ++r)
                    #pragma unroll
                    for (int c = 0; c < 8; ++c)
                        acc[r][c] = fmaf(av[r], bv[c], acc[r][c]);
            }
        }
        #pragma unroll
        for (int c = 0; c < 8; ++c) {
            const int j = j0 + tx * 8 + c;
            const float dj = Dsf[tx * 8 + c];
            #pragma unroll
            for (int r = 0; r < 8; ++r) {
                const int ig = i0 + ty * 8 + r;
                float v = fmaf(-2.0f, acc[r][c], dj);
                v = (j == ig) ? FLT_MAX : v;
                const bool lt = v < m1[r];
                m2[r] = fminf(m2[r], fmaxf(m1[r], v));
                m1[r] = fminf(m1[r], v);
                i1[r] = lt ? j : i1[r];
            }
        }
    }
    __syncthreads();
    #pragma unroll
    for (int r = 0; r < 8; ++r) {
        float* s = &Scrf[((ty * 8 + r) * 32 + tx) * 3];
        s[0] = m1[r]; s[1] = __int_as_float(i1[r]); s[2] = m2[r];
    }
    __syncthreads();
    if (tid < FTI) {
        float M1 = FLT_MAX, M2 = FLT_MAX; int I1 = 0;
        for (int t = 0; t < 32; ++t) {
            const float* s = &Scrf[(tid * 32 + t) * 3];
            const float v1 = s[0]; const int ii = __float_as_int(s[1]);
            const float v2 = s[2];
            if (v1 < M1 || (v1 == M1 && ii < I1)) {
                M2 = fminf(M2, M1); M1 = v1; I1 = ii;
            } else {
                M2 = fminf(M2, v1);
            }
            M2 = fminf(M2, v2);
        }
        const int   gi = i0 + tid;
        const float di = dbf[gi];
        const float d1 = sqrtf(fmaxf(di + M1, 0.0f) + 1e-9f);
        const float d2 = sqrtf(fmaxf(di + M2, 0.0f) + 1e-9f);
        const float e  = expf(d1);
        const float pred = (d1 / d2 < 0.6f) ? 2.0f / (1.0f + e)
                                            : 2.0f / (1.0f + 2.0f * e);
        out[(size_t)batch * NN + gi] = pred;
        out[(size_t)NB * NN + (size_t)batch * NN + gi] = (float)I1;
    }
}

extern "C" void kernel_launch(void* const* d_in, const int* in_sizes, int n_in,
                              void* d_out, int out_size, void* d_ws, size_t ws_size,
                              hipStream_t stream) {
    const float* x = (const float*)d_in[0];
    float* out     = (float*)d_out;
    const size_t n_elem = (size_t)NB * NN * NC;
    const size_t need = n_elem * 4                       // interleaved hi/lo f16
                      + (size_t)NB * NN * 4              // diag
                      + (size_t)NB * NN * 2 * 3 * 4;     // per-half partials
    if (ws_size >= need) {
        f16*   xhl  = (f16*)d_ws;
        float* diag = (float*)(xhl + n_elem * 2);
        float* part = diag + (size_t)NB * NN;
        prep_kernel<<<dim3(NB * NN / 4), dim3(256), 0, stream>>>(x, xhl, diag);
        fcm_mfma<<<dim3(512), dim3(256), 0, stream>>>(xhl, diag, part);
        combine_kernel<<<dim3(NB * NN / 256), dim3(256), 0, stream>>>(part, diag, out);
    } else {
        float* diag = (float*)d_ws;
        diag_kernel<<<dim3(NB * NN / 4), dim3(256), 0, stream>>>(x, diag);
        fcm_fallback<<<dim3(256), dim3(256), 0, stream>>>(x, diag, out);
    }
}

// Round 6
// 208.909 us; speedup vs baseline: 1.1632x; 1.0927x over previous
//
#include <hip/hip_runtime.h>
#include <cfloat>

#define NB 4
#define NN 4096
#define NC 256

typedef _Float16 f16;
typedef _Float16 f16x8 __attribute__((ext_vector_type(8)));
typedef float f32x16 __attribute__((ext_vector_type(16)));

__device__ __forceinline__ void gl_lds16(const void* g, void* l) {
    __builtin_amdgcn_global_load_lds(
        (const __attribute__((address_space(1))) unsigned int*)g,
        (__attribute__((address_space(3))) unsigned int*)l, 16, 0, 0);
}

// ---- prep: fp32 -> f16 hi/lo, band-transposed layout + diag ----
// xT[band][g][r]: band = row/64, granule g in 0..63 (g = k8*2 + hilo; 16 B = 8 f16),
// r = row%64. Byte addr = band*65536 + g*1024 + r*16. One block per band.
__global__ __launch_bounds__(256) void prep_kernel(const float* __restrict__ x,
                                                   f16* __restrict__ xt,
                                                   float* __restrict__ diag) {
    __shared__ f16 LT[64 * 64 * 8];      // [g][r] granules, 64 KB
    const int band = blockIdx.x;         // 0..255 (global row band)
    const int t = threadIdx.x;
    {   // phase 1: row r = t>>2, k-quarter kq = t&3 (k = kq*64..+63)
        const int r = t >> 2, kq = t & 3;
        const float* src = x + ((size_t)band * 64 + r) * 256 + kq * 64;
        float s = 0.f;
        #pragma unroll
        for (int i = 0; i < 8; ++i) {    // k8-granule = kq*8+i
            const float4 a = *(const float4*)(src + i * 8);
            const float4 b = *(const float4*)(src + i * 8 + 4);
            float vv[8] = {a.x, a.y, a.z, a.w, b.x, b.y, b.z, b.w};
            union { f16 h[8]; f16x8 v; } H, L;
            #pragma unroll
            for (int k = 0; k < 8; ++k) {
                H.h[k] = (f16)vv[k];
                L.h[k] = (f16)(vv[k] - (float)H.h[k]);
                s = fmaf(vv[k], vv[k], s);
            }
            const int g = (kq * 8 + i) * 2;
            *(f16x8*)&LT[((g + 0) * 64 + r) * 8] = H.v;
            *(f16x8*)&LT[((g + 1) * 64 + r) * 8] = L.v;
        }
        s += __shfl_xor(s, 1, 64);
        s += __shfl_xor(s, 2, 64);
        if (kq == 0) diag[band * 64 + r] = s;
    }
    __syncthreads();
    {   // phase 2: coalesced write-out. r = t&63, granules (t>>6)*16..+15
        const int r = t & 63, g0 = (t >> 6) * 16;
        f16* dst = xt + (size_t)band * 32768;
        #pragma unroll
        for (int gi = 0; gi < 16; ++gi) {
            const int g = g0 + gi;
            *(f16x8*)(dst + g * 512 + r * 8) = *(const f16x8*)&LT[(g * 64 + r) * 8];
        }
    }
}

// ---------------- main MFMA kernel: barrier-free K-loop ----------------
// Grid 512 = 4 batch x 64 band x 2 j-half; 256 thr (4 waves, col-split 128 each).
// A (64 rows x full K) staged once to LDS; B frags stream global->VGPR,
// software-pipelined one K16-chunk ahead (ping-pong reg buffers). No K-loop barriers.
#define TI 64
#define TJ 512
#define JH 2048
#define NCH (NC / 16)    // 16
#define NJT (JH / TJ)    // 4
#define NQ  (NJT * NCH)  // 64

struct BFrag { f16x8 h[4]; f16x8 l[4]; };

__device__ __forceinline__ void load_b(BFrag& f, const f16* __restrict__ xbt,
                                       int jcol0, int kc, int gh, int l31) {
    const int gofs = (kc * 4 + gh * 2) * 512;
    #pragma unroll
    for (int ct = 0; ct < 4; ++ct) {
        const int c = jcol0 + ct * 32 + l31;
        const f16* p = xbt + (size_t)(c >> 6) * 32768 + gofs + (c & 63) * 8;
        f.h[ct] = *(const f16x8*)p;
        f.l[ct] = *(const f16x8*)(p + 512);
    }
}

__device__ __forceinline__ void mfma_chunk(f32x16 (&acc)[2][4], const f16* AT,
                                           const BFrag& b, int kc, int gh, int l31) {
    const int gofs = (kc * 4 + gh * 2) * 512;
    f16x8 ah[2], al[2];
    #pragma unroll
    for (int rt = 0; rt < 2; ++rt) {
        const f16* p = AT + gofs + (rt * 32 + l31) * 8;
        ah[rt] = *(const f16x8*)p;
        al[rt] = *(const f16x8*)(p + 512);
    }
    #pragma unroll
    for (int rt = 0; rt < 2; ++rt)
        #pragma unroll
        for (int ct = 0; ct < 4; ++ct)
            acc[rt][ct] = __builtin_amdgcn_mfma_f32_32x32x16_f16(ah[rt], b.h[ct], acc[rt][ct], 0, 0, 0);
    #pragma unroll
    for (int rt = 0; rt < 2; ++rt)
        #pragma unroll
        for (int ct = 0; ct < 4; ++ct)
            acc[rt][ct] = __builtin_amdgcn_mfma_f32_32x32x16_f16(ah[rt], b.l[ct], acc[rt][ct], 0, 0, 0);
    #pragma unroll
    for (int rt = 0; rt < 2; ++rt)
        #pragma unroll
        for (int ct = 0; ct < 4; ++ct)
            acc[rt][ct] = __builtin_amdgcn_mfma_f32_32x32x16_f16(al[rt], b.h[ct], acc[rt][ct], 0, 0, 0);
}

__global__ __launch_bounds__(256, 2) void fcm_mfma(const f16* __restrict__ xt,
                                                   const float* __restrict__ diag,
                                                   float* __restrict__ part) {
    __shared__ f16 AT[64 * 512];         // 64 KB: A band, [granule][row]
    __shared__ float St[TI * 4 * 3];     //  3 KB: per-(row,wave) running top-2

    const int tid   = threadIdx.x;
    const int bx    = blockIdx.x;
    const int batch = (bx & 7) >> 1;     // batch -> XCD pair (L2 locality)
    const int jh    = bx & 1;
    const int band  = bx >> 3;           // 0..63
    const int i0    = band * TI;
    const int jbase = jh * JH;

    const f16* __restrict__ xbt = xt + (size_t)batch * 2097152;  // 64 bands * 32768
    const float* __restrict__ db = diag + (size_t)batch * NN;

    const int w    = tid >> 6;           // col slice (128 cols)
    const int lane = tid & 63;
    const int gh   = lane >> 5;
    const int l31  = lane & 31;

    // first B chunk into regs (in flight during A staging)
    BFrag b0, b1;
    load_b(b0, xbt, jbase + w * 128, 0, gh, l31);

    // stage A band (once): 16 instrs/wave, coalesced, [g][row] layout
    {
        const f16* asrc = xbt + (size_t)band * 32768;
        #pragma unroll
        for (int gi = 0; gi < 16; ++gi) {
            const int g = w * 16 + gi;
            gl_lds16(asrc + g * 512 + lane * 8, AT + g * 512 + lane * 8);
        }
    }
    for (int idx = tid; idx < TI * 4 * 3; idx += 256) St[idx] = FLT_MAX;
    __syncthreads();                     // the ONLY barrier before the merge

    f32x16 acc[2][4];
    #pragma unroll
    for (int rt = 0; rt < 2; ++rt)
        #pragma unroll
        for (int ct = 0; ct < 4; ++ct)
            #pragma unroll
            for (int p = 0; p < 16; ++p) acc[rt][ct][p] = 0.f;

    #pragma unroll 1
    for (int q = 0; q < NQ; q += 2) {
        // prefetch q+1 (always exists: NQ even)
        load_b(b1, xbt, jbase + ((q + 1) >> 4) * TJ + w * 128, (q + 1) & 15, gh, l31);
        mfma_chunk(acc, AT, b0, q & 15, gh, l31);
        if (q + 2 < NQ)
            load_b(b0, xbt, jbase + ((q + 2) >> 4) * TJ + w * 128, (q + 2) & 15, gh, l31);
        mfma_chunk(acc, AT, b1, (q + 1) & 15, gh, l31);

        if (((q + 1) & 15) == 15) {      // end of j-tile: fold + reset acc
            const int jt = (q + 1) >> 4;
            int jv[4]; float djv[4];
            #pragma unroll
            for (int ct = 0; ct < 4; ++ct) {
                jv[ct]  = jbase + jt * TJ + w * 128 + ct * 32 + l31;
                djv[ct] = db[jv[ct]];
            }
            float r1 = FLT_MAX, r2 = FLT_MAX; int ri = 0x7fffffff;
            #pragma unroll
            for (int s = 0; s < 32; ++s) {
                const int rt  = s >> 4, reg = s & 15;
                const int rg  = i0 + rt * 32 + (gh << 2) + (reg & 3) + ((reg >> 2) << 3);
                float a1 = FLT_MAX, a2 = FLT_MAX; int ai = 0x7fffffff;
                #pragma unroll
                for (int ct = 0; ct < 4; ++ct) {
                    float v = fmaf(-2.0f, acc[rt][ct][reg], djv[ct]);
                    v = (jv[ct] == rg) ? FLT_MAX : v;      // mask self
                    const bool lt = v < a1;                // strict: ascending j
                    a2 = fminf(a2, fmaxf(a1, v));
                    a1 = fminf(a1, v);
                    ai = lt ? jv[ct] : ai;
                }
                #pragma unroll
                for (int msk = 1; msk < 32; msk <<= 1) {   // within gh half
                    const float o1 = __shfl_xor(a1, msk, 64);
                    const float o2 = __shfl_xor(a2, msk, 64);
                    const int   oi = __shfl_xor(ai, msk, 64);
                    const bool take = (o1 < a1) || (o1 == a1 && oi < ai);
                    const float keep = take ? a1 : o1;
                    a2 = fminf(fminf(a2, o2), keep);
                    a1 = take ? o1 : a1;
                    ai = take ? oi : ai;
                }
                const bool sel = (l31 == s);
                r1 = sel ? a1 : r1;
                r2 = sel ? a2 : r2;
                ri = sel ? ai : ri;
            }
            {   // RMW this wave's St column; rows disjoint across lanes
                const int s_rt = l31 >> 4, s_reg = l31 & 15;
                const int rrow = s_rt * 32 + (gh << 2) + (s_reg & 3) + ((s_reg >> 2) << 3);
                float* p = &St[(rrow * 4 + w) * 3];
                const float o1 = p[0]; const int oi = __float_as_int(p[1]); const float o2 = p[2];
                const bool take = (o1 < r1) || (o1 == r1 && oi < ri);
                const float keep = take ? r1 : o1;
                p[0] = take ? o1 : r1;
                p[1] = __int_as_float(take ? oi : ri);
                p[2] = fminf(fminf(r2, o2), keep);
            }
            #pragma unroll
            for (int rt = 0; rt < 2; ++rt)
                #pragma unroll
                for (int ct = 0; ct < 4; ++ct)
                    #pragma unroll
                    for (int p = 0; p < 16; ++p) acc[rt][ct][p] = 0.f;
        }
    }

    __syncthreads();
    if (tid < TI) {
        float M1 = FLT_MAX, M2 = FLT_MAX; int I1 = 0x7fffffff;
        #pragma unroll
        for (int t = 0; t < 4; ++t) {
            const float* p = &St[(tid * 4 + t) * 3];
            const float o1 = p[0]; const int oi = __float_as_int(p[1]); const float o2 = p[2];
            const bool take = (o1 < M1) || (o1 == M1 && oi < I1);
            const float keep = take ? M1 : o1;
            M2 = fminf(fminf(M2, o2), keep);
            M1 = take ? o1 : M1;
            I1 = take ? oi : I1;
        }
        float* qo = part + (((size_t)batch * NN + i0 + tid) * 2 + jh) * 3;
        qo[0] = M1; qo[1] = __int_as_float(I1); qo[2] = M2;
    }
}

// ---- combine the two j-half partials, compute outputs ----
__global__ __launch_bounds__(256) void combine_kernel(const float* __restrict__ part,
                                                      const float* __restrict__ diag,
                                                      float* __restrict__ out) {
    const int g = blockIdx.x * 256 + threadIdx.x;      // 0..16383
    float M1 = FLT_MAX, M2 = FLT_MAX; int I1 = 0x7fffffff;
    #pragma unroll
    for (int h = 0; h < 2; ++h) {
        const float* p = part + ((size_t)g * 2 + h) * 3;
        const float o1 = p[0]; const int oi = __float_as_int(p[1]); const float o2 = p[2];
        const bool take = (o1 < M1) || (o1 == M1 && oi < I1);
        const float keep = take ? M1 : o1;
        M2 = fminf(fminf(M2, o2), keep);
        M1 = take ? o1 : M1;
        I1 = take ? oi : I1;
    }
    const float di = diag[g];
    const float d1 = sqrtf(fmaxf(di + M1, 0.0f) + 1e-9f);
    const float d2 = sqrtf(fmaxf(di + M2, 0.0f) + 1e-9f);
    const float e  = expf(d1);
    const float pred = (d1 / d2 < 0.6f) ? 2.0f / (1.0f + e)
                                        : 2.0f / (1.0f + 2.0f * e);
    out[g] = pred;
    out[(size_t)NB * NN + g] = (float)I1;
}

// ---------------- fp32 fallback (round-1, known-correct) if ws too small ----------------
__global__ __launch_bounds__(256) void diag_kernel(const float* __restrict__ x,
                                                   float* __restrict__ diag) {
    const int lane = threadIdx.x & 63;
    const int wave = threadIdx.x >> 6;
    const int row  = (blockIdx.x << 2) + wave;
    const float4 v = ((const float4*)(x + (size_t)row * NC))[lane];
    float s = v.x * v.x + v.y * v.y + v.z * v.z + v.w * v.w;
    #pragma unroll
    for (int off = 32; off; off >>= 1) s += __shfl_xor(s, off, 64);
    if (lane == 0) diag[row] = s;
}

#define FTI 64
#define FTJ 256
#define FKC 16

__global__ __launch_bounds__(256) void fcm_fallback(const float* __restrict__ x,
                                                    const float* __restrict__ diag,
                                                    float* __restrict__ out) {
    __shared__ float Asf[FKC * FTI];
    __shared__ float Bsf[FKC * FTJ];
    __shared__ float Dsf[FTJ];
    __shared__ float Scrf[FTI * 32 * 3];

    const int tid = threadIdx.x;
    const int bx  = blockIdx.x;
    const int batch = (bx & 7) >> 1;
    const int tile  = ((bx >> 3) << 1) | (bx & 1);
    const int i0    = tile * FTI;
    const float* __restrict__ xbf = x + (size_t)batch * NN * NC;
    const float* __restrict__ dbf = diag + (size_t)batch * NN;
    const int tx = tid & 31;
    const int ty = tid >> 5;
    const int sr  = tid & 63;
    const int sk0 = (tid >> 6) << 2;

    float m1[8], m2[8]; int i1[8];
    #pragma unroll
    for (int r = 0; r < 8; ++r) { m1[r] = FLT_MAX; m2[r] = FLT_MAX; i1[r] = 0; }

    for (int jt = 0; jt < NN / FTJ; ++jt) {
        const int j0 = jt * FTJ;
        __syncthreads();
        Dsf[tid] = dbf[j0 + tid];
        float acc[8][8];
        #pragma unroll
        for (int r = 0; r < 8; ++r)
            #pragma unroll
            for (int c = 0; c < 8; ++c) acc[r][c] = 0.0f;
        float4 pa  = *(const float4*)(xbf + (size_t)(i0 + sr) * NC + sk0);
        const float* bsrc = xbf + (size_t)(j0 + tid) * NC;
        float4 pb0 = *(const float4*)(bsrc + 0);
        float4 pb1 = *(const float4*)(bsrc + 4);
        float4 pb2 = *(const float4*)(bsrc + 8);
        float4 pb3 = *(const float4*)(bsrc + 12);
        for (int kc = 0; kc < NC / FKC; ++kc) {
            __syncthreads();
            Asf[(sk0 + 0) * FTI + sr] = pa.x;
            Asf[(sk0 + 1) * FTI + sr] = pa.y;
            Asf[(sk0 + 2) * FTI + sr] = pa.z;
            Asf[(sk0 + 3) * FTI + sr] = pa.w;
            Bsf[ 0 * FTJ + tid] = pb0.x; Bsf[ 1 * FTJ + tid] = pb0.y;
            Bsf[ 2 * FTJ + tid] = pb0.z; Bsf[ 3 * FTJ + tid] = pb0.w;
            Bsf[ 4 * FTJ + tid] = pb1.x; Bsf[ 5 * FTJ + tid] = pb1.y;
            Bsf[ 6 * FTJ + tid] = pb1.z; Bsf[ 7 * FTJ + tid] = pb1.w;
            Bsf[ 8 * FTJ + tid] = pb2.x; Bsf[ 9 * FTJ + tid] = pb2.y;
            Bsf[10 * FTJ + tid] = pb2.z; Bsf[11 * FTJ + tid] = pb2.w;
            Bsf[12 * FTJ + tid] = pb3.x; Bsf[13 * FTJ + tid] = pb3.y;
            Bsf[14 * FTJ + tid] = pb3.z; Bsf[15 * FTJ + tid] = pb3.w;
            if (kc + 1 < NC / FKC) {
                const int kb = (kc + 1) * FKC;
                pa  = *(const float4*)(xbf + (size_t)(i0 + sr) * NC + kb + sk0);
                pb0 = *(const float4*)(bsrc + kb + 0);
                pb1 = *(const float4*)(bsrc + kb + 4);
                pb2 = *(const float4*)(bsrc + kb + 8);
                pb3 = *(const float4*)(bsrc + kb + 12);
            }
            __syncthreads();
            #pragma unroll
            for (int k = 0; k < FKC; ++k) {
                float av[8], bv[8];
                *(float4*)&av[0] = *(const float4*)&Asf[k * FTI + ty * 8];
                *(float4*)&av[4] = *(const float4*)&Asf[k * FTI + ty * 8 + 4];
                *(float4*)&bv[0] = *(const float4*)&Bsf[k * FTJ + tx * 8];
                *(float4*)&bv[4] = *(const float4*)&Bsf[k * FTJ + tx * 8 + 4];
                #pragma unroll
                for (int r = 0; r < 8; ++r)
                    #pragma unroll
                    for (int c = 0; c < 8; ++c)
                        acc[r][c] = fmaf(av[r], bv[c], acc[r][c]);
            }
        }
        #pragma unroll
        for (int c = 0; c < 8; ++c) {
            const int j = j0 + tx * 8 + c;
            const float dj = Dsf[tx * 8 + c];
            #pragma unroll
            for (int r = 0; r < 8; ++r) {
                const int ig = i0 + ty * 8 + r;
                float v = fmaf(-2.0f, acc[r][c], dj);
                v = (j == ig) ? FLT_MAX : v;
                const bool lt = v < m1[r];
                m2[r] = fminf(m2[r], fmaxf(m1[r], v));
                m1[r] = fminf(m1[r], v);
                i1[r] = lt ? j : i1[r];
            }
        }
    }
    __syncthreads();
    #pragma unroll
    for (int r = 0; r < 8; ++r) {
        float* s = &Scrf[((ty * 8 + r) * 32 + tx) * 3];
        s[0] = m1[r]; s[1] = __int_as_float(i1[r]); s[2] = m2[r];
    }
    __syncthreads();
    if (tid < FTI) {
        float M1 = FLT_MAX, M2 = FLT_MAX; int I1 = 0;
        for (int t = 0; t < 32; ++t) {
            const float* s = &Scrf[(tid * 32 + t) * 3];
            const float v1 = s[0]; const int ii = __float_as_int(s[1]);
            const float v2 = s[2];
            if (v1 < M1 || (v1 == M1 && ii < I1)) {
                M2 = fminf(M2, M1); M1 = v1; I1 = ii;
            } else {
                M2 = fminf(M2, v1);
            }
            M2 = fminf(M2, v2);
        }
        const int   gi = i0 + tid;
        const float di = dbf[gi];
        const float d1 = sqrtf(fmaxf(di + M1, 0.0f) + 1e-9f);
        const float d2 = sqrtf(fmaxf(di + M2, 0.0f) + 1e-9f);
        const float e  = expf(d1);
        const float pred = (d1 / d2 < 0.6f) ? 2.0f / (1.0f + e)
                                            : 2.0f / (1.0f + 2.0f * e);
        out[(size_t)batch * NN + gi] = pred;
        out[(size_t)NB * NN + (size_t)batch * NN + gi] = (float)I1;
    }
}

extern "C" void kernel_launch(void* const* d_in, const int* in_sizes, int n_in,
                              void* d_out, int out_size, void* d_ws, size_t ws_size,
                              hipStream_t stream) {
    const float* x = (const float*)d_in[0];
    float* out     = (float*)d_out;
    const size_t n_elem = (size_t)NB * NN * NC;
    const size_t need = n_elem * 4                       // band-transposed hi/lo f16
                      + (size_t)NB * NN * 4              // diag
                      + (size_t)NB * NN * 2 * 3 * 4;     // per-half partials
    if (ws_size >= need) {
        f16*   xt   = (f16*)d_ws;
        float* diag = (float*)(xt + (size_t)NB * NN * 512);
        float* part = diag + (size_t)NB * NN;
        prep_kernel<<<dim3(NB * NN / 64), dim3(256), 0, stream>>>(x, xt, diag);
        fcm_mfma<<<dim3(512), dim3(256), 0, stream>>>(xt, diag, part);
        combine_kernel<<<dim3(NB * NN / 256), dim3(256), 0, stream>>>(part, diag, out);
    } else {
        float* diag = (float*)d_ws;
        diag_kernel<<<dim3(NB * NN / 4), dim3(256), 0, stream>>>(x, diag);
        fcm_fallback<<<dim3(256), dim3(256), 0, stream>>>(x, diag, out);
    }
}